// Round 8
// baseline (298.743 us; speedup 1.0000x reference)
//
#include <hip/hip_runtime.h>
#include <hip/hip_bf16.h>

#define B_   2
#define T_   2048
#define C_   1024
#define H_   16
#define DK_  64

typedef __bf16 bf16x8 __attribute__((ext_vector_type(8)));
typedef __bf16 bf16x4v __attribute__((ext_vector_type(4)));
typedef float  f32x4  __attribute__((ext_vector_type(4)));
typedef unsigned short u16;
typedef u16 u16x4 __attribute__((ext_vector_type(4)));
typedef u16 u16x8 __attribute__((ext_vector_type(8)));

static __device__ __forceinline__ u16 f2bf(float f) {
    unsigned u = __float_as_uint(f);
    u += 0x7fffu + ((u >> 16) & 1u);   // RNE
    return (u16)(u >> 16);
}
static __device__ __forceinline__ float bf2f(u16 h) {
    return __uint_as_float(((unsigned)h) << 16);
}

// async global->LDS 16B: LDS dest is wave-uniform base + lane*16; global src per-lane
static __device__ __forceinline__ void async16(void* l, const void* g) {
    __builtin_amdgcn_global_load_lds(
        (const __attribute__((address_space(1))) unsigned int*)g,
        (__attribute__((address_space(3))) unsigned int*)l, 16, 0, 0);
}

// ============================================================
// pack_a_hl: fp32 [4096][1024] -> tiles [mt][kt32][128 rows x (hi64B|lo64B)], swizzled
// ============================================================
__global__ __launch_bounds__(256) void pack_a_hl(const float* __restrict__ src, char* __restrict__ dst) {
    const int mt = blockIdx.x, kt = blockIdx.y, t = threadIdx.x;
    const int r = t >> 1, half = t & 1;
    const float* s = src + (size_t)(mt * 128 + r) * 1024 + kt * 32 + half * 16;
    float f[16];
    #pragma unroll
    for (int i = 0; i < 4; ++i) *(float4*)&f[i * 4] = ((const float4*)s)[i];
    u16 hi[16] __attribute__((aligned(16))), lo[16] __attribute__((aligned(16)));
    #pragma unroll
    for (int e = 0; e < 16; ++e) { hi[e] = f2bf(f[e]); lo[e] = f2bf(f[e] - bf2f(hi[e])); }
    char* tb = dst + ((size_t)mt * 32 + kt) * 16384;
    const int sw = (r & 7) << 4;
    #pragma unroll
    for (int j = 0; j < 2; ++j) {
        int g = half * 2 + j;
        *(u16x8*)(tb + ((r * 128 + g * 16) ^ sw))      = *(u16x8*)&hi[j * 8];
        *(u16x8*)(tb + ((r * 128 + 64 + g * 16) ^ sw)) = *(u16x8*)&lo[j * 8];
    }
}

// ============================================================
// pack_a_s: fp32 [4096][1024] -> tiles [mt][kt64][128 rows x 128B single-bf16], swizzled
// ============================================================
__global__ __launch_bounds__(256) void pack_a_s(const float* __restrict__ src, char* __restrict__ dst) {
    const int mt = blockIdx.x, kt = blockIdx.y, t = threadIdx.x;
    const int r = t >> 1, half = t & 1;
    const float* s = src + (size_t)(mt * 128 + r) * 1024 + kt * 64 + half * 32;
    float f[32];
    #pragma unroll
    for (int i = 0; i < 8; ++i) *(float4*)&f[i * 4] = ((const float4*)s)[i];
    u16 hv[32] __attribute__((aligned(16)));
    #pragma unroll
    for (int e = 0; e < 32; ++e) hv[e] = f2bf(f[e]);
    char* tb = dst + ((size_t)mt * 16 + kt) * 16384;
    const int sw = (r & 7) << 4;
    #pragma unroll
    for (int j = 0; j < 4; ++j) {
        int g = half * 4 + j;
        *(u16x8*)(tb + ((r * 128 + g * 16) ^ sw)) = *(u16x8*)&hv[j * 8];
    }
}

// ============================================================
// pack_bt_hl<BKT>: W [K][N] fp32 -> transposed tiles
//   [nt][kt][128 n-rows x (hi BKT*2B | lo BKT*2B)], swizzled. LDS transpose.
// ============================================================
template <int BKT>
__global__ __launch_bounds__(256) void pack_bt_hl(const float* __restrict__ W, char* __restrict__ dst,
                                                  int N, int nkt) {
    __shared__ float Ls[BKT][132];
    const int nt = blockIdx.x, kt = blockIdx.y, t = threadIdx.x;
    #pragma unroll
    for (int p = 0; p < BKT / 32; ++p) {
        int kr = p * 32 + (t >> 3), c8 = t & 7;
        const float* s = W + (size_t)(kt * BKT + kr) * N + nt * 128 + c8 * 16;
        #pragma unroll
        for (int i = 0; i < 4; ++i) *(float4*)&Ls[kr][c8 * 16 + i * 4] = ((const float4*)s)[i];
    }
    __syncthreads();
    const int nr = t >> 1, half = t & 1;
    constexpr int KH = BKT / 2;
    constexpr int ROWB = BKT * 4;          // 128 or 256
    constexpr int TILEB = 128 * ROWB;      // 16384 or 32768
    char* tb = dst + ((size_t)nt * nkt + kt) * TILEB;
    u16 hi[KH] __attribute__((aligned(16))), lo[KH] __attribute__((aligned(16)));
    #pragma unroll
    for (int e = 0; e < KH; ++e) {
        float x = Ls[half * KH + e][nr];
        hi[e] = f2bf(x); lo[e] = f2bf(x - bf2f(hi[e]));
    }
    const int sw = (nr & 7) << 4;
    #pragma unroll
    for (int j = 0; j < KH / 8; ++j) {
        int g = half * (KH / 8) + j;
        *(u16x8*)(tb + ((nr * ROWB + g * 16) ^ sw))            = *(u16x8*)&hi[j * 8];
        *(u16x8*)(tb + ((nr * ROWB + ROWB / 2 + g * 16) ^ sw)) = *(u16x8*)&lo[j * 8];
    }
}

// ============================================================
// kv_pack: k_out/v_out [bh][t][64] fp32 -> per-(bh,kt) 16KB tiles
//   Kp tile: [64 tok-rows x 128B d] hi at [0,8K), lo at [8K,16K), swizzled
//   Vp tile: [64 d-rows x 128B tok] hi/lo, swizzled (transposed via LDS)
// ============================================================
__global__ __launch_bounds__(256) void kv_pack(
    const float* __restrict__ k_in, const float* __restrict__ v_in,
    char* __restrict__ kp, char* __restrict__ vp)
{
    __shared__ float Ls[64][68];
    const int bh = blockIdx.x, kt = blockIdx.y, t = threadIdx.x;
    const float* Kb = k_in + (size_t)bh * T_ * DK_ + (size_t)kt * 64 * DK_;
    const float* Vb = v_in + (size_t)bh * T_ * DK_ + (size_t)kt * 64 * DK_;
    char* ktb = kp + ((size_t)bh * 32 + kt) * 16384;
    char* vtb = vp + ((size_t)bh * 32 + kt) * 16384;
    const int row = t >> 2, qtr = t & 3;

    // ---- K: row-major hi/lo ----
    {
        float f[16];
        #pragma unroll
        for (int i = 0; i < 4; ++i)
            *(float4*)&f[i * 4] = ((const float4*)(Kb + (size_t)row * 64 + qtr * 16))[i];
        u16 hi[16] __attribute__((aligned(16))), lo[16] __attribute__((aligned(16)));
        #pragma unroll
        for (int e = 0; e < 16; ++e) { hi[e] = f2bf(f[e]); lo[e] = f2bf(f[e] - bf2f(hi[e])); }
        const int sw = (row & 7) << 4;
        *(u16x8*)(ktb + ((row * 128 + qtr * 32) ^ sw))             = *(u16x8*)&hi[0];
        *(u16x8*)(ktb + ((row * 128 + qtr * 32 + 16) ^ sw))        = *(u16x8*)&hi[8];
        *(u16x8*)(ktb + 8192 + ((row * 128 + qtr * 32) ^ sw))      = *(u16x8*)&lo[0];
        *(u16x8*)(ktb + 8192 + ((row * 128 + qtr * 32 + 16) ^ sw)) = *(u16x8*)&lo[8];
    }

    // ---- V: stage fp32 tile, transpose-emit hi/lo ----
    #pragma unroll
    for (int i = 0; i < 4; ++i)
        *(float4*)&Ls[row][qtr * 16 + i * 4] = ((const float4*)(Vb + (size_t)row * 64 + qtr * 16))[i];
    __syncthreads();
    {
        const int dd = t >> 2, tc2 = t & 3;    // d-row, 16-token chunk
        float f[16];
        #pragma unroll
        for (int k = 0; k < 16; ++k) f[k] = Ls[tc2 * 16 + k][dd];
        u16 hi[16] __attribute__((aligned(16))), lo[16] __attribute__((aligned(16)));
        #pragma unroll
        for (int e = 0; e < 16; ++e) { hi[e] = f2bf(f[e]); lo[e] = f2bf(f[e] - bf2f(hi[e])); }
        const int sw = (dd & 7) << 4;
        *(u16x8*)(vtb + ((dd * 128 + tc2 * 32) ^ sw))             = *(u16x8*)&hi[0];
        *(u16x8*)(vtb + ((dd * 128 + tc2 * 32 + 16) ^ sw))        = *(u16x8*)&hi[8];
        *(u16x8*)(vtb + 8192 + ((dd * 128 + tc2 * 32) ^ sw))      = *(u16x8*)&lo[0];
        *(u16x8*)(vtb + 8192 + ((dd * 128 + tc2 * 32 + 16) ^ sw)) = *(u16x8*)&lo[8];
    }
}

// ============================================================
// qkv GEMM: C = A(hi/lo) x B(hi/lo), 3-product. 128x128 tile, BK=32, 4 waves.
// ============================================================
__global__ __launch_bounds__(256, 2) void qkv_gemm_bf16(
    const char* __restrict__ xp, const char* __restrict__ wqp,
    const float* __restrict__ bqkv,
    float* __restrict__ qy, float* __restrict__ k_out, float* __restrict__ v_out)
{
    __shared__ __align__(16) char Alds[16384];
    __shared__ __align__(16) char Blds[16384];
    const int mt = blockIdx.x, nt = blockIdx.y;
    const int t = threadIdx.x, lane = t & 63, w = t >> 6;
    const int g = lane >> 4, r15 = lane & 15;
    const int wm = w >> 1, wn = w & 1;

    int aoff[4][2], boff[4][2];
    #pragma unroll
    for (int s = 0; s < 4; ++s) {
        int ar = wm * 64 + s * 16 + r15, sa = (ar & 7) << 4;
        aoff[s][0] = (ar * 128 + g * 16) ^ sa;
        aoff[s][1] = (ar * 128 + 64 + g * 16) ^ sa;
        int br = wn * 64 + s * 16 + r15, sb = (br & 7) << 4;
        boff[s][0] = (br * 128 + g * 16) ^ sb;
        boff[s][1] = (br * 128 + 64 + g * 16) ^ sb;
    }

    f32x4 acc[4][4];
    #pragma unroll
    for (int i = 0; i < 4; ++i)
        #pragma unroll
        for (int j = 0; j < 4; ++j) acc[i][j] = (f32x4){0.f, 0.f, 0.f, 0.f};

    const char* Abase = xp + (size_t)mt * 32 * 16384 + w * 4096 + lane * 16;
    const char* Bbase = wqp + (size_t)nt * 32 * 16384 + w * 4096 + lane * 16;
    char* la = Alds + w * 4096;
    char* lb = Blds + w * 4096;

    for (int kt = 0; kt < 32; ++kt) {
        #pragma unroll
        for (int i = 0; i < 4; ++i) {
            async16(la + i * 1024, Abase + kt * 16384 + i * 1024);
            async16(lb + i * 1024, Bbase + kt * 16384 + i * 1024);
        }
        __syncthreads();
        bf16x8 af[4][2], bf[4][2];
        #pragma unroll
        for (int s = 0; s < 4; ++s) {
            af[s][0] = *(const bf16x8*)(Alds + aoff[s][0]);
            af[s][1] = *(const bf16x8*)(Alds + aoff[s][1]);
            bf[s][0] = *(const bf16x8*)(Blds + boff[s][0]);
            bf[s][1] = *(const bf16x8*)(Blds + boff[s][1]);
        }
        #pragma unroll
        for (int i = 0; i < 4; ++i)
            #pragma unroll
            for (int j = 0; j < 4; ++j) {
                acc[i][j] = __builtin_amdgcn_mfma_f32_16x16x32_bf16(af[i][0], bf[j][0], acc[i][j], 0, 0, 0);
                acc[i][j] = __builtin_amdgcn_mfma_f32_16x16x32_bf16(af[i][0], bf[j][1], acc[i][j], 0, 0, 0);
                acc[i][j] = __builtin_amdgcn_mfma_f32_16x16x32_bf16(af[i][1], bf[j][0], acc[i][j], 0, 0, 0);
            }
        __syncthreads();
    }

    const int n0 = nt * 128;
    const int sec = n0 >> 10;                 // 0=q 1=k 2=v (uniform per block)
    float* kv = (sec == 1) ? k_out : v_out;
    #pragma unroll
    for (int i = 0; i < 4; ++i) {
        int mbase = mt * 128 + wm * 64 + i * 16 + g * 4;
        #pragma unroll
        for (int j = 0; j < 4; ++j) {
            int n = n0 + wn * 64 + j * 16 + r15;
            float bias = bqkv[n];
            int c = n & 1023;
            #pragma unroll
            for (int r = 0; r < 4; ++r) {
                int m = mbase + r;
                int bb = m >> 11, tt = m & 2047;
                float val = acc[i][j][r] + bias;
                if (sec == 0)
                    qy[((size_t)bb * T_ + tt) * C_ + c] = val;
                else
                    kv[(((size_t)bb * H_ + (c >> 6)) * T_ + tt) * DK_ + (c & 63)] = val;
            }
        }
    }
}

// ============================================================
// proj GEMM: C = A(single bf16) x B(hi/lo), 2-product. BK=64, 4 waves.
// ============================================================
__global__ __launch_bounds__(256, 2) void proj_gemm_bf16(
    const char* __restrict__ yap, const char* __restrict__ wpp,
    const float* __restrict__ bp, float* __restrict__ y)
{
    __shared__ __align__(16) char Alds[16384];
    __shared__ __align__(16) char Blds[32768];
    const int mt = blockIdx.x, nt = blockIdx.y;
    const int t = threadIdx.x, lane = t & 63, w = t >> 6;
    const int g = lane >> 4, r15 = lane & 15;
    const int wm = w >> 1, wn = w & 1;

    int aoff[4][2], boffh[4][2], boffl[4][2];
    #pragma unroll
    for (int s = 0; s < 4; ++s) {
        int ar = wm * 64 + s * 16 + r15, sa = (ar & 7) << 4;
        int br = wn * 64 + s * 16 + r15, sb = (br & 7) << 4;
        #pragma unroll
        for (int kk = 0; kk < 2; ++kk) {
            aoff[s][kk]  = (ar * 128 + (kk * 4 + g) * 16) ^ sa;
            boffh[s][kk] = (br * 256 + (kk * 4 + g) * 16) ^ sb;
            boffl[s][kk] = (br * 256 + 128 + (kk * 4 + g) * 16) ^ sb;
        }
    }

    f32x4 acc[4][4];
    #pragma unroll
    for (int i = 0; i < 4; ++i)
        #pragma unroll
        for (int j = 0; j < 4; ++j) acc[i][j] = (f32x4){0.f, 0.f, 0.f, 0.f};

    const char* Abase = yap + (size_t)mt * 16 * 16384 + w * 4096 + lane * 16;
    const char* Bbase = wpp + (size_t)nt * 16 * 32768 + w * 8192 + lane * 16;
    char* la = Alds + w * 4096;
    char* lb = Blds + w * 8192;

    for (int kt = 0; kt < 16; ++kt) {
        #pragma unroll
        for (int i = 0; i < 4; ++i)
            async16(la + i * 1024, Abase + kt * 16384 + i * 1024);
        #pragma unroll
        for (int i = 0; i < 8; ++i)
            async16(lb + i * 1024, Bbase + kt * 32768 + i * 1024);
        __syncthreads();
        #pragma unroll
        for (int kk = 0; kk < 2; ++kk) {
            bf16x8 af[4], bh[4], bl[4];
            #pragma unroll
            for (int s = 0; s < 4; ++s) {
                af[s] = *(const bf16x8*)(Alds + aoff[s][kk]);
                bh[s] = *(const bf16x8*)(Blds + boffh[s][kk]);
                bl[s] = *(const bf16x8*)(Blds + boffl[s][kk]);
            }
            #pragma unroll
            for (int i = 0; i < 4; ++i)
                #pragma unroll
                for (int j = 0; j < 4; ++j) {
                    acc[i][j] = __builtin_amdgcn_mfma_f32_16x16x32_bf16(af[i], bh[j], acc[i][j], 0, 0, 0);
                    acc[i][j] = __builtin_amdgcn_mfma_f32_16x16x32_bf16(af[i], bl[j], acc[i][j], 0, 0, 0);
                }
        }
        __syncthreads();
    }

    #pragma unroll
    for (int i = 0; i < 4; ++i) {
        int mbase = mt * 128 + wm * 64 + i * 16 + g * 4;
        #pragma unroll
        for (int j = 0; j < 4; ++j) {
            int n = nt * 128 + wn * 64 + j * 16 + r15;
            float bias = bp[n];
            #pragma unroll
            for (int r = 0; r < 4; ++r)
                y[(size_t)(mbase + r) * 1024 + n] = acc[i][j][r] + bias;
        }
    }
}

// ============================================================
// attention: K/V pre-packed; P single-bf16 (native cvt_pk casts);
//   exp2-domain softmax (Q pre-scaled by log2e/8); T13 defer-rescale.
//   LDS 40KB -> 4 blocks/CU.
// ============================================================
#define PS_   0        // 8KB: P bf16 rows (Q-hi temp during staging)
#define KS_H  8192     // (Q-lo temp during staging)
#define KS_L  16384
#define VT_H  24576
#define VT_L  32768

__global__ __launch_bounds__(256) void attn_mfma_kernel(
    float* qyatt,                     // [B,T,C]: Q in, yatt out (per-cell read-then-write)
    const char* __restrict__ Kp,      // [bh][kt] 16KB tiles
    const char* __restrict__ Vp)      // [bh][kt] 16KB tiles (transposed)
{
    __shared__ __align__(16) char lds[40960];

    const int bh   = blockIdx.x;           // 0..31
    const int qt   = 31 - (int)blockIdx.y; // LPT: longest first
    const int qb   = qt * 64;
    const int t    = threadIdx.x;
    const int lane = t & 63;
    const int w    = t >> 6;
    const int g    = lane >> 4;
    const int r15  = lane & 15;
    const int b    = bh >> 4, h = bh & 15;

    const float* Qb = qyatt + ((size_t)b * T_ + qb) * C_ + h * 64;
    const float QSCALE = 0.125f * 1.44269504088896f;   // 1/sqrt(dk) * log2(e)

    // ---- stage Q (64 rows x 64 d) bf16 hi/lo (hi->PS_, lo->KS_H temp) ----
    #pragma unroll
    for (int di = 0; di < 4; ++di) {
        int fidx = di * 256 + t;
        int row  = fidx >> 4;
        int c4   = fidx & 15;
        float4 f = ((const float4*)(Qb + (size_t)row * C_))[c4];
        f.x *= QSCALE; f.y *= QSCALE; f.z *= QSCALE; f.w *= QSCALE;
        u16 h0 = f2bf(f.x), h1 = f2bf(f.y), h2 = f2bf(f.z), h3 = f2bf(f.w);
        u16 l0 = f2bf(f.x - bf2f(h0)), l1 = f2bf(f.y - bf2f(h1));
        u16 l2 = f2bf(f.z - bf2f(h2)), l3 = f2bf(f.w - bf2f(h3));
        int off = (row * 128 + c4 * 8) ^ ((row & 7) << 4);
        u16x4 hv = {h0, h1, h2, h3};
        u16x4 lv = {l0, l1, l2, l3};
        *(u16x4*)(lds + PS_  + off) = hv;
        *(u16x4*)(lds + KS_H + off) = lv;
    }
    __syncthreads();

    bf16x8 qfh[2], qfl[2];
    const int prow = w * 16 + r15;
    #pragma unroll
    for (int dc = 0; dc < 2; ++dc) {
        int off = (prow * 128 + dc * 64 + g * 16) ^ ((prow & 7) << 4);
        qfh[dc] = *(const bf16x8*)(lds + PS_  + off);
        qfl[dc] = *(const bf16x8*)(lds + KS_H + off);
    }

    f32x4 zero4 = {0.f, 0.f, 0.f, 0.f};
    f32x4 o[4];
    o[0] = zero4; o[1] = zero4; o[2] = zero4; o[3] = zero4;
    float mrun = -1e30f, lrun = 0.f;
    const int qglob = qb + w * 16 + r15;

    const int nt = qt + 1;
    for (int kt = 0; kt < nt; ++kt) {
        const int j0 = kt * 64;
        __syncthreads();   // prev tile consumed / Q frags hoisted
        {
            const char* Kg = Kp + ((size_t)bh * 32 + kt) * 16384 + w * 4096 + lane * 16;
            const char* Vg = Vp + ((size_t)bh * 32 + kt) * 16384 + w * 4096 + lane * 16;
            char* lk = lds + KS_H + w * 4096;
            char* lv = lds + VT_H + w * 4096;
            #pragma unroll
            for (int i = 0; i < 4; ++i) {
                async16(lk + i * 1024, Kg + i * 1024);
                async16(lv + i * 1024, Vg + i * 1024);
            }
        }
        __syncthreads();

        // ---- S^T = K.Q^T (log2 units): 4 k-subtiles of 16 ----
        float sv[4][4];
        const bool diag = (kt == qt);
        #pragma unroll
        for (int st = 0; st < 4; ++st) {
            f32x4 acc = zero4;
            int krow = st * 16 + r15;
            #pragma unroll
            for (int dc = 0; dc < 2; ++dc) {
                int off = (krow * 128 + dc * 64 + g * 16) ^ ((krow & 7) << 4);
                bf16x8 kh = *(const bf16x8*)(lds + KS_H + off);
                bf16x8 kl = *(const bf16x8*)(lds + KS_L + off);
                acc = __builtin_amdgcn_mfma_f32_16x16x32_bf16(kh, qfh[dc], acc, 0, 0, 0);
                acc = __builtin_amdgcn_mfma_f32_16x16x32_bf16(kh, qfl[dc], acc, 0, 0, 0);
                acc = __builtin_amdgcn_mfma_f32_16x16x32_bf16(kl, qfh[dc], acc, 0, 0, 0);
            }
            #pragma unroll
            for (int r = 0; r < 4; ++r) {
                float x = acc[r];
                if (diag) {
                    int kg = j0 + st * 16 + g * 4 + r;
                    if (kg > qglob) x = -1e30f;
                }
                sv[st][r] = x;
            }
        }

        // ---- online softmax in exp2 domain, defer-rescale (T13, THR=11.5) ----
        float tm = sv[0][0];
        #pragma unroll
        for (int st = 0; st < 4; ++st)
            #pragma unroll
            for (int r = 0; r < 4; ++r) tm = fmaxf(tm, sv[st][r]);
        tm = fmaxf(tm, __shfl_xor(tm, 16));
        tm = fmaxf(tm, __shfl_xor(tm, 32));
        if (__any(tm > mrun + 11.5f)) {        // wave-uniform rescale (rare)
            float mnew = fmaxf(mrun, tm);
            float resc = exp2f(mrun - mnew);
            mrun = mnew;
            lrun *= resc;
            o[0] *= resc; o[1] *= resc; o[2] *= resc; o[3] *= resc;
        }

        float ps = 0.f;
        #pragma unroll
        for (int st = 0; st < 4; ++st)
            #pragma unroll
            for (int r = 0; r < 4; ++r) {
                float p = exp2f(sv[st][r] - mrun);   // bounded by 2^11.5
                sv[st][r] = p;
                ps += p;
            }
        ps += __shfl_xor(ps, 16);
        ps += __shfl_xor(ps, 32);
        lrun += ps;

        // ---- write P single-bf16 (native casts -> cvt_pk), wave-private rows ----
        #pragma unroll
        for (int st = 0; st < 4; ++st) {
            bf16x4v pb = { (__bf16)sv[st][0], (__bf16)sv[st][1],
                           (__bf16)sv[st][2], (__bf16)sv[st][3] };
            int off = (prow * 128 + (st * 16 + g * 4) * 2) ^ ((prow & 7) << 4);
            *(bf16x4v*)(lds + PS_ + off) = pb;
        }

        // ---- O^T += V^T . P^T  (V hi/lo x P single: 2-product) ----
        bf16x8 pf[2];
        #pragma unroll
        for (int kc = 0; kc < 2; ++kc) {
            int off = (prow * 128 + kc * 64 + g * 16) ^ ((prow & 7) << 4);
            pf[kc] = *(const bf16x8*)(lds + PS_ + off);
        }
        #pragma unroll
        for (int dt = 0; dt < 4; ++dt) {
            int vrow = dt * 16 + r15;
            #pragma unroll
            for (int kc = 0; kc < 2; ++kc) {
                int off = (vrow * 128 + kc * 64 + g * 16) ^ ((vrow & 7) << 4);
                bf16x8 vh = *(const bf16x8*)(lds + VT_H + off);
                bf16x8 vl = *(const bf16x8*)(lds + VT_L + off);
                o[dt] = __builtin_amdgcn_mfma_f32_16x16x32_bf16(vh, pf[kc], o[dt], 0, 0, 0);
                o[dt] = __builtin_amdgcn_mfma_f32_16x16x32_bf16(vl, pf[kc], o[dt], 0, 0, 0);
            }
        }
    }

    // ---- epilogue: O^T[d][q] -> yatt[b][q][h*64+d] ----
    const float inv = 1.f / lrun;
    float* yo = qyatt + ((size_t)b * T_ + qglob) * C_ + h * DK_;
    #pragma unroll
    for (int dt = 0; dt < 4; ++dt)
        #pragma unroll
        for (int r = 0; r < 4; ++r)
            yo[dt * 16 + g * 4 + r] = o[dt][r] * inv;
}

// ============================================================
extern "C" void kernel_launch(void* const* d_in, const int* in_sizes, int n_in,
                              void* d_out, int out_size, void* d_ws, size_t ws_size,
                              hipStream_t stream) {
    const float* x     = (const float*)d_in[0];
    const float* Wqkv  = (const float*)d_in[1];
    const float* bqkv  = (const float*)d_in[2];
    const float* Wproj = (const float*)d_in[3];
    const float* bproj = (const float*)d_in[4];

    float* y     = (float*)d_out;                 // [B,T,C]: q fp32 -> yatt -> final y
    float* k_out = y + (size_t)4194304;           // [B,H,T,DK] (final output)
    float* v_out = y + (size_t)8388608;           // [B,H,T,DK] (final output)

    char* ws = (char*)d_ws;                       // 32 MB, lifetime-aliased:
    char* xp  = ws;                               // [0,16M)  x packed        (phase 1-2)
    char* wqp = ws + ((size_t)16 << 20);          // [16M,28M) Wqkv packed    (phase 1-2)
    char* Kp  = ws;                               // [0,16M)  K packed        (phase 3-4)
    char* Vp  = ws + ((size_t)16 << 20);          // [16M,32M) V^T packed     (phase 3-4)
    char* yap = ws;                               // [0,8M)   yatt packed     (phase 5-6)
    char* wpp = ws + ((size_t)8 << 20);           // [8M,12M) Wproj packed    (phase 5-6)

    pack_a_hl     <<<dim3(32, 32), 256, 0, stream>>>(x, xp);
    pack_bt_hl<32><<<dim3(24, 32), 256, 0, stream>>>(Wqkv, wqp, 3072, 32);
    qkv_gemm_bf16 <<<dim3(32, 24), 256, 0, stream>>>(xp, wqp, bqkv, y, k_out, v_out);
    kv_pack       <<<dim3(32, 32), 256, 0, stream>>>(k_out, v_out, Kp, Vp);
    attn_mfma_kernel<<<dim3(32, 32), 256, 0, stream>>>(y, Kp, Vp);
    pack_a_s      <<<dim3(32, 16), 256, 0, stream>>>(y, yap);
    pack_bt_hl<64><<<dim3(8, 16), 256, 0, stream>>>(Wproj, wpp, 1024, 16);
    proj_gemm_bf16<<<dim3(32, 8), 256, 0, stream>>>(yap, wpp, bproj, y);
}

// Round 11
// 288.224 us; speedup vs baseline: 1.0365x; 1.0365x over previous
//
#include <hip/hip_runtime.h>
#include <hip/hip_bf16.h>

#define B_   2
#define T_   2048
#define C_   1024
#define H_   16
#define DK_  64

typedef __bf16 bf16x8 __attribute__((ext_vector_type(8)));
typedef __bf16 bf16x4v __attribute__((ext_vector_type(4)));
typedef float  f32x4  __attribute__((ext_vector_type(4)));
typedef unsigned short u16;
typedef u16 u16x4 __attribute__((ext_vector_type(4)));
typedef u16 u16x8 __attribute__((ext_vector_type(8)));

static __device__ __forceinline__ u16 f2bf(float f) {
    unsigned u = __float_as_uint(f);
    u += 0x7fffu + ((u >> 16) & 1u);   // RNE
    return (u16)(u >> 16);
}
static __device__ __forceinline__ float bf2f(u16 h) {
    return __uint_as_float(((unsigned)h) << 16);
}

// async global->LDS 16B: LDS dest is wave-uniform base + lane*16; global src per-lane
static __device__ __forceinline__ void async16(void* l, const void* g) {
    __builtin_amdgcn_global_load_lds(
        (const __attribute__((address_space(1))) unsigned int*)g,
        (__attribute__((address_space(3))) unsigned int*)l, 16, 0, 0);
}

// ============================================================
// pack_a_hl: fp32 [4096][1024] -> tiles [mt][kt32][128 rows x (hi64B|lo64B)], swizzled
// ============================================================
__global__ __launch_bounds__(256) void pack_a_hl(const float* __restrict__ src, char* __restrict__ dst) {
    const int mt = blockIdx.x, kt = blockIdx.y, t = threadIdx.x;
    const int r = t >> 1, half = t & 1;
    const float* s = src + (size_t)(mt * 128 + r) * 1024 + kt * 32 + half * 16;
    float f[16];
    #pragma unroll
    for (int i = 0; i < 4; ++i) *(float4*)&f[i * 4] = ((const float4*)s)[i];
    u16 hi[16] __attribute__((aligned(16))), lo[16] __attribute__((aligned(16)));
    #pragma unroll
    for (int e = 0; e < 16; ++e) { hi[e] = f2bf(f[e]); lo[e] = f2bf(f[e] - bf2f(hi[e])); }
    char* tb = dst + ((size_t)mt * 32 + kt) * 16384;
    const int sw = (r & 7) << 4;
    #pragma unroll
    for (int j = 0; j < 2; ++j) {
        int g = half * 2 + j;
        *(u16x8*)(tb + ((r * 128 + g * 16) ^ sw))      = *(u16x8*)&hi[j * 8];
        *(u16x8*)(tb + ((r * 128 + 64 + g * 16) ^ sw)) = *(u16x8*)&lo[j * 8];
    }
}

// ============================================================
// pack_a_s: fp32 [4096][1024] -> tiles [mt][kt64][128 rows x 128B single-bf16], swizzled
// ============================================================
__global__ __launch_bounds__(256) void pack_a_s(const float* __restrict__ src, char* __restrict__ dst) {
    const int mt = blockIdx.x, kt = blockIdx.y, t = threadIdx.x;
    const int r = t >> 1, half = t & 1;
    const float* s = src + (size_t)(mt * 128 + r) * 1024 + kt * 64 + half * 32;
    float f[32];
    #pragma unroll
    for (int i = 0; i < 8; ++i) *(float4*)&f[i * 4] = ((const float4*)s)[i];
    u16 hv[32] __attribute__((aligned(16)));
    #pragma unroll
    for (int e = 0; e < 32; ++e) hv[e] = f2bf(f[e]);
    char* tb = dst + ((size_t)mt * 16 + kt) * 16384;
    const int sw = (r & 7) << 4;
    #pragma unroll
    for (int j = 0; j < 4; ++j) {
        int g = half * 4 + j;
        *(u16x8*)(tb + ((r * 128 + g * 16) ^ sw)) = *(u16x8*)&hv[j * 8];
    }
}

// ============================================================
// pack_bt_hl<BKT>: W [K][N] fp32 -> transposed tiles
//   [nt][kt][128 n-rows x (hi BKT*2B | lo BKT*2B)], swizzled. LDS transpose.
// ============================================================
template <int BKT>
__global__ __launch_bounds__(256) void pack_bt_hl(const float* __restrict__ W, char* __restrict__ dst,
                                                  int N, int nkt) {
    __shared__ float Ls[BKT][132];
    const int nt = blockIdx.x, kt = blockIdx.y, t = threadIdx.x;
    #pragma unroll
    for (int p = 0; p < BKT / 32; ++p) {
        int kr = p * 32 + (t >> 3), c8 = t & 7;
        const float* s = W + (size_t)(kt * BKT + kr) * N + nt * 128 + c8 * 16;
        #pragma unroll
        for (int i = 0; i < 4; ++i) *(float4*)&Ls[kr][c8 * 16 + i * 4] = ((const float4*)s)[i];
    }
    __syncthreads();
    const int nr = t >> 1, half = t & 1;
    constexpr int KH = BKT / 2;
    constexpr int ROWB = BKT * 4;          // 128 or 256
    constexpr int TILEB = 128 * ROWB;      // 16384 or 32768
    char* tb = dst + ((size_t)nt * nkt + kt) * TILEB;
    u16 hi[KH] __attribute__((aligned(16))), lo[KH] __attribute__((aligned(16)));
    #pragma unroll
    for (int e = 0; e < KH; ++e) {
        float x = Ls[half * KH + e][nr];
        hi[e] = f2bf(x); lo[e] = f2bf(x - bf2f(hi[e]));
    }
    const int sw = (nr & 7) << 4;
    #pragma unroll
    for (int j = 0; j < KH / 8; ++j) {
        int g = half * (KH / 8) + j;
        *(u16x8*)(tb + ((nr * ROWB + g * 16) ^ sw))            = *(u16x8*)&hi[j * 8];
        *(u16x8*)(tb + ((nr * ROWB + ROWB / 2 + g * 16) ^ sw)) = *(u16x8*)&lo[j * 8];
    }
}

// ============================================================
// kv_pack: k_out/v_out [bh][t][64] fp32 -> per-(bh,kt) 16KB tiles
//   Kp tile: [64 tok-rows x 128B d] hi at [0,8K), lo at [8K,16K), swizzled
//   Vp tile: [64 d-rows x 128B tok] hi/lo, swizzled (transposed via LDS)
// ============================================================
__global__ __launch_bounds__(256) void kv_pack(
    const float* __restrict__ k_in, const float* __restrict__ v_in,
    char* __restrict__ kp, char* __restrict__ vp)
{
    __shared__ float Ls[64][68];
    const int bh = blockIdx.x, kt = blockIdx.y, t = threadIdx.x;
    const float* Kb = k_in + (size_t)bh * T_ * DK_ + (size_t)kt * 64 * DK_;
    const float* Vb = v_in + (size_t)bh * T_ * DK_ + (size_t)kt * 64 * DK_;
    char* ktb = kp + ((size_t)bh * 32 + kt) * 16384;
    char* vtb = vp + ((size_t)bh * 32 + kt) * 16384;
    const int row = t >> 2, qtr = t & 3;

    // ---- K: row-major hi/lo ----
    {
        float f[16];
        #pragma unroll
        for (int i = 0; i < 4; ++i)
            *(float4*)&f[i * 4] = ((const float4*)(Kb + (size_t)row * 64 + qtr * 16))[i];
        u16 hi[16] __attribute__((aligned(16))), lo[16] __attribute__((aligned(16)));
        #pragma unroll
        for (int e = 0; e < 16; ++e) { hi[e] = f2bf(f[e]); lo[e] = f2bf(f[e] - bf2f(hi[e])); }
        const int sw = (row & 7) << 4;
        *(u16x8*)(ktb + ((row * 128 + qtr * 32) ^ sw))             = *(u16x8*)&hi[0];
        *(u16x8*)(ktb + ((row * 128 + qtr * 32 + 16) ^ sw))        = *(u16x8*)&hi[8];
        *(u16x8*)(ktb + 8192 + ((row * 128 + qtr * 32) ^ sw))      = *(u16x8*)&lo[0];
        *(u16x8*)(ktb + 8192 + ((row * 128 + qtr * 32 + 16) ^ sw)) = *(u16x8*)&lo[8];
    }

    // ---- V: stage fp32 tile, transpose-emit hi/lo ----
    #pragma unroll
    for (int i = 0; i < 4; ++i)
        *(float4*)&Ls[row][qtr * 16 + i * 4] = ((const float4*)(Vb + (size_t)row * 64 + qtr * 16))[i];
    __syncthreads();
    {
        const int dd = t >> 2, tc2 = t & 3;    // d-row, 16-token chunk
        float f[16];
        #pragma unroll
        for (int k = 0; k < 16; ++k) f[k] = Ls[tc2 * 16 + k][dd];
        u16 hi[16] __attribute__((aligned(16))), lo[16] __attribute__((aligned(16)));
        #pragma unroll
        for (int e = 0; e < 16; ++e) { hi[e] = f2bf(f[e]); lo[e] = f2bf(f[e] - bf2f(hi[e])); }
        const int sw = (dd & 7) << 4;
        *(u16x8*)(vtb + ((dd * 128 + tc2 * 32) ^ sw))             = *(u16x8*)&hi[0];
        *(u16x8*)(vtb + ((dd * 128 + tc2 * 32 + 16) ^ sw))        = *(u16x8*)&hi[8];
        *(u16x8*)(vtb + 8192 + ((dd * 128 + tc2 * 32) ^ sw))      = *(u16x8*)&lo[0];
        *(u16x8*)(vtb + 8192 + ((dd * 128 + tc2 * 32 + 16) ^ sw)) = *(u16x8*)&lo[8];
    }
}

// ============================================================
// qkv GEMM: C = A(hi/lo) x B(hi/lo), 3-product. 128x128 tile, BK=32, 4 waves.
// ============================================================
__global__ __launch_bounds__(256, 2) void qkv_gemm_bf16(
    const char* __restrict__ xp, const char* __restrict__ wqp,
    const float* __restrict__ bqkv,
    float* __restrict__ qy, float* __restrict__ k_out, float* __restrict__ v_out)
{
    __shared__ __align__(16) char Alds[16384];
    __shared__ __align__(16) char Blds[16384];
    const int mt = blockIdx.x, nt = blockIdx.y;
    const int t = threadIdx.x, lane = t & 63, w = t >> 6;
    const int g = lane >> 4, r15 = lane & 15;
    const int wm = w >> 1, wn = w & 1;

    int aoff[4][2], boff[4][2];
    #pragma unroll
    for (int s = 0; s < 4; ++s) {
        int ar = wm * 64 + s * 16 + r15, sa = (ar & 7) << 4;
        aoff[s][0] = (ar * 128 + g * 16) ^ sa;
        aoff[s][1] = (ar * 128 + 64 + g * 16) ^ sa;
        int br = wn * 64 + s * 16 + r15, sb = (br & 7) << 4;
        boff[s][0] = (br * 128 + g * 16) ^ sb;
        boff[s][1] = (br * 128 + 64 + g * 16) ^ sb;
    }

    f32x4 acc[4][4];
    #pragma unroll
    for (int i = 0; i < 4; ++i)
        #pragma unroll
        for (int j = 0; j < 4; ++j) acc[i][j] = (f32x4){0.f, 0.f, 0.f, 0.f};

    const char* Abase = xp + (size_t)mt * 32 * 16384 + w * 4096 + lane * 16;
    const char* Bbase = wqp + (size_t)nt * 32 * 16384 + w * 4096 + lane * 16;
    char* la = Alds + w * 4096;
    char* lb = Blds + w * 4096;

    for (int kt = 0; kt < 32; ++kt) {
        #pragma unroll
        for (int i = 0; i < 4; ++i) {
            async16(la + i * 1024, Abase + kt * 16384 + i * 1024);
            async16(lb + i * 1024, Bbase + kt * 16384 + i * 1024);
        }
        __syncthreads();
        bf16x8 af[4][2], bf[4][2];
        #pragma unroll
        for (int s = 0; s < 4; ++s) {
            af[s][0] = *(const bf16x8*)(Alds + aoff[s][0]);
            af[s][1] = *(const bf16x8*)(Alds + aoff[s][1]);
            bf[s][0] = *(const bf16x8*)(Blds + boff[s][0]);
            bf[s][1] = *(const bf16x8*)(Blds + boff[s][1]);
        }
        #pragma unroll
        for (int i = 0; i < 4; ++i)
            #pragma unroll
            for (int j = 0; j < 4; ++j) {
                acc[i][j] = __builtin_amdgcn_mfma_f32_16x16x32_bf16(af[i][0], bf[j][0], acc[i][j], 0, 0, 0);
                acc[i][j] = __builtin_amdgcn_mfma_f32_16x16x32_bf16(af[i][0], bf[j][1], acc[i][j], 0, 0, 0);
                acc[i][j] = __builtin_amdgcn_mfma_f32_16x16x32_bf16(af[i][1], bf[j][0], acc[i][j], 0, 0, 0);
            }
        __syncthreads();
    }

    const int n0 = nt * 128;
    const int sec = n0 >> 10;                 // 0=q 1=k 2=v (uniform per block)
    float* kv = (sec == 1) ? k_out : v_out;
    #pragma unroll
    for (int i = 0; i < 4; ++i) {
        int mbase = mt * 128 + wm * 64 + i * 16 + g * 4;
        #pragma unroll
        for (int j = 0; j < 4; ++j) {
            int n = n0 + wn * 64 + j * 16 + r15;
            float bias = bqkv[n];
            int c = n & 1023;
            #pragma unroll
            for (int r = 0; r < 4; ++r) {
                int m = mbase + r;
                int bb = m >> 11, tt = m & 2047;
                float val = acc[i][j][r] + bias;
                if (sec == 0)
                    qy[((size_t)bb * T_ + tt) * C_ + c] = val;
                else
                    kv[(((size_t)bb * H_ + (c >> 6)) * T_ + tt) * DK_ + (c & 63)] = val;
            }
        }
    }
}

// ============================================================
// proj GEMM: C = A(single bf16) x B(hi/lo), 2-product. BK=64, 4 waves.
// ============================================================
__global__ __launch_bounds__(256, 2) void proj_gemm_bf16(
    const char* __restrict__ yap, const char* __restrict__ wpp,
    const float* __restrict__ bp, float* __restrict__ y)
{
    __shared__ __align__(16) char Alds[16384];
    __shared__ __align__(16) char Blds[32768];
    const int mt = blockIdx.x, nt = blockIdx.y;
    const int t = threadIdx.x, lane = t & 63, w = t >> 6;
    const int g = lane >> 4, r15 = lane & 15;
    const int wm = w >> 1, wn = w & 1;

    int aoff[4][2], boffh[4][2], boffl[4][2];
    #pragma unroll
    for (int s = 0; s < 4; ++s) {
        int ar = wm * 64 + s * 16 + r15, sa = (ar & 7) << 4;
        int br = wn * 64 + s * 16 + r15, sb = (br & 7) << 4;
        #pragma unroll
        for (int kk = 0; kk < 2; ++kk) {
            aoff[s][kk]  = (ar * 128 + (kk * 4 + g) * 16) ^ sa;
            boffh[s][kk] = (br * 256 + (kk * 4 + g) * 16) ^ sb;
            boffl[s][kk] = (br * 256 + 128 + (kk * 4 + g) * 16) ^ sb;
        }
    }

    f32x4 acc[4][4];
    #pragma unroll
    for (int i = 0; i < 4; ++i)
        #pragma unroll
        for (int j = 0; j < 4; ++j) acc[i][j] = (f32x4){0.f, 0.f, 0.f, 0.f};

    const char* Abase = yap + (size_t)mt * 16 * 16384 + w * 4096 + lane * 16;
    const char* Bbase = wpp + (size_t)nt * 16 * 32768 + w * 8192 + lane * 16;
    char* la = Alds + w * 4096;
    char* lb = Blds + w * 8192;

    for (int kt = 0; kt < 16; ++kt) {
        #pragma unroll
        for (int i = 0; i < 4; ++i)
            async16(la + i * 1024, Abase + kt * 16384 + i * 1024);
        #pragma unroll
        for (int i = 0; i < 8; ++i)
            async16(lb + i * 1024, Bbase + kt * 32768 + i * 1024);
        __syncthreads();
        #pragma unroll
        for (int kk = 0; kk < 2; ++kk) {
            bf16x8 af[4], bh[4], bl[4];
            #pragma unroll
            for (int s = 0; s < 4; ++s) {
                af[s] = *(const bf16x8*)(Alds + aoff[s][kk]);
                bh[s] = *(const bf16x8*)(Blds + boffh[s][kk]);
                bl[s] = *(const bf16x8*)(Blds + boffl[s][kk]);
            }
            #pragma unroll
            for (int i = 0; i < 4; ++i)
                #pragma unroll
                for (int j = 0; j < 4; ++j) {
                    acc[i][j] = __builtin_amdgcn_mfma_f32_16x16x32_bf16(af[i], bh[j], acc[i][j], 0, 0, 0);
                    acc[i][j] = __builtin_amdgcn_mfma_f32_16x16x32_bf16(af[i], bl[j], acc[i][j], 0, 0, 0);
                }
        }
        __syncthreads();
    }

    #pragma unroll
    for (int i = 0; i < 4; ++i) {
        int mbase = mt * 128 + wm * 64 + i * 16 + g * 4;
        #pragma unroll
        for (int j = 0; j < 4; ++j) {
            int n = nt * 128 + wn * 64 + j * 16 + r15;
            float bias = bp[n];
            #pragma unroll
            for (int r = 0; r < 4; ++r)
                y[(size_t)(mbase + r) * 1024 + n] = acc[i][j][r] + bias;
        }
    }
}

// ============================================================
// attention: 128 q-rows/block, 8 waves; K/V double-buffered with
//   stage-ahead (T3 2-phase, ONE barrier/tile); P single-bf16;
//   exp2-domain softmax; T13 defer-rescale.
//   LDS 80KB: P 16K | buf0 (K16K|V16K) | buf1 (K16K|V16K) -> 2 blocks/CU.
// ============================================================
#define PS_    0          // 16KB: P bf16 rows [128][128B]
#define BUF0_  16384      // K hi/lo 8K+8K, V hi/lo 8K+8K
#define BUF1_  49152
#define QT_H   16384      // Q temp (pre-loop) overlays buf0
#define QT_L   32768

__global__ __launch_bounds__(512) void attn_mfma_kernel(
    float* qyatt,                     // [B,T,C]: Q in, yatt out (per-cell read-then-write)
    const char* __restrict__ Kp,      // [bh][kt] 16KB tiles
    const char* __restrict__ Vp)      // [bh][kt] 16KB tiles (transposed)
{
    __shared__ __align__(16) char lds[81920];

    const int bh   = blockIdx.x;           // 0..31
    const int by   = blockIdx.y;           // 0..15
    const int qt   = (by < 8) ? (15 - by) : (by - 8);  // LPT + long/short CU pairing
    const int qb   = qt * 128;
    const int t    = threadIdx.x;          // 0..511
    const int lane = t & 63;
    const int w    = t >> 6;               // wave 0..7
    const int g    = lane >> 4;
    const int r15  = lane & 15;
    const int b    = bh >> 4, h = bh & 15;

    const float* Qb = qyatt + ((size_t)b * T_ + qb) * C_ + h * 64;
    const float QSCALE = 0.125f * 1.44269504088896f;   // 1/sqrt(dk) * log2(e)

    // ---- stage Q (128 rows x 64 d) bf16 hi/lo into buf0 temp ----
    #pragma unroll
    for (int di = 0; di < 4; ++di) {
        int fidx = di * 512 + t;        // 0..2047 float4s
        int row  = fidx >> 4;           // 0..127
        int c4   = fidx & 15;
        float4 f = ((const float4*)(Qb + (size_t)row * C_))[c4];
        f.x *= QSCALE; f.y *= QSCALE; f.z *= QSCALE; f.w *= QSCALE;
        u16 h0 = f2bf(f.x), h1 = f2bf(f.y), h2 = f2bf(f.z), h3 = f2bf(f.w);
        u16 l0 = f2bf(f.x - bf2f(h0)), l1 = f2bf(f.y - bf2f(h1));
        u16 l2 = f2bf(f.z - bf2f(h2)), l3 = f2bf(f.w - bf2f(h3));
        int off = (row * 128 + c4 * 8) ^ ((row & 7) << 4);
        u16x4 hv = {h0, h1, h2, h3};
        u16x4 lv = {l0, l1, l2, l3};
        *(u16x4*)(lds + QT_H + off) = hv;
        *(u16x4*)(lds + QT_L + off) = lv;
    }
    __syncthreads();

    bf16x8 qfh[2], qfl[2];
    const int prow = w * 16 + r15;         // this lane's q row within block, 0..127
    #pragma unroll
    for (int dc = 0; dc < 2; ++dc) {
        int off = (prow * 128 + dc * 64 + g * 16) ^ ((prow & 7) << 4);
        qfh[dc] = *(const bf16x8*)(lds + QT_H + off);
        qfl[dc] = *(const bf16x8*)(lds + QT_L + off);
    }
    __syncthreads();   // all waves done reading Q temp before buf0 is overwritten

    f32x4 zero4 = {0.f, 0.f, 0.f, 0.f};
    f32x4 o[4];
    o[0] = zero4; o[1] = zero4; o[2] = zero4; o[3] = zero4;
    float mrun = -1e30f, lrun = 0.f;
    const int qglob = qb + prow;
    const int ktd   = (qb + w * 16) >> 6;  // wave's diagonal kv-tile (wave-uniform)
    const int nt    = qt * 2 + 2;

    // stage: wave w loads its 4KB slice; waves 0-3 -> K, 4-7 -> V
    const char* KVg[2] = {
        Kp + (size_t)bh * 32 * 16384 + (w & 3) * 4096 + lane * 16,
        Vp + (size_t)bh * 32 * 16384 + (w & 3) * 4096 + lane * 16 };
    const char* gsrc = KVg[w >> 2];
    char* ldst0 = lds + BUF0_ + (w >> 2) * 16384 + (w & 3) * 4096;
    char* ldst1 = lds + BUF1_ + (w >> 2) * 16384 + (w & 3) * 4096;

    // prologue: stage tile 0 into buf0
    #pragma unroll
    for (int i = 0; i < 4; ++i)
        async16(ldst0 + i * 1024, gsrc + i * 1024);
    __syncthreads();   // implicit vmcnt(0): tile 0 resident

    for (int kt = 0; kt < nt; ++kt) {
        // ---- stage-ahead: issue loads for tile kt+1 into the other buffer ----
        if (kt + 1 < nt) {
            char* ld = ((kt + 1) & 1) ? ldst1 : ldst0;
            const char* gs = gsrc + (size_t)(kt + 1) * 16384;
            #pragma unroll
            for (int i = 0; i < 4; ++i)
                async16(ld + i * 1024, gs + i * 1024);
        }

        // ---- compute tile kt (skip past this wave's diagonal) ----
        if (kt <= ktd) {
            const char* KB = lds + ((kt & 1) ? BUF1_ : BUF0_);
            const char* KH = KB,         * KL = KB + 8192;
            const char* VH = KB + 16384, * VL = KB + 24576;
            const int j0 = kt * 64;
            const bool diag = (kt == ktd);

            float sv[4][4];
            #pragma unroll
            for (int st = 0; st < 4; ++st) {
                f32x4 acc = zero4;
                int krow = st * 16 + r15;
                #pragma unroll
                for (int dc = 0; dc < 2; ++dc) {
                    int off = (krow * 128 + dc * 64 + g * 16) ^ ((krow & 7) << 4);
                    bf16x8 kh = *(const bf16x8*)(KH + off);
                    bf16x8 kl = *(const bf16x8*)(KL + off);
                    acc = __builtin_amdgcn_mfma_f32_16x16x32_bf16(kh, qfh[dc], acc, 0, 0, 0);
                    acc = __builtin_amdgcn_mfma_f32_16x16x32_bf16(kh, qfl[dc], acc, 0, 0, 0);
                    acc = __builtin_amdgcn_mfma_f32_16x16x32_bf16(kl, qfh[dc], acc, 0, 0, 0);
                }
                #pragma unroll
                for (int r = 0; r < 4; ++r) {
                    float x = acc[r];
                    if (diag) {
                        int kg = j0 + st * 16 + g * 4 + r;
                        if (kg > qglob) x = -1e30f;
                    }
                    sv[st][r] = x;
                }
            }

            // ---- online softmax (exp2 domain), T13 defer-rescale ----
            float tm = sv[0][0];
            #pragma unroll
            for (int st = 0; st < 4; ++st)
                #pragma unroll
                for (int r = 0; r < 4; ++r) tm = fmaxf(tm, sv[st][r]);
            tm = fmaxf(tm, __shfl_xor(tm, 16));
            tm = fmaxf(tm, __shfl_xor(tm, 32));
            if (__any(tm > mrun + 11.5f)) {
                float mnew = fmaxf(mrun, tm);
                float resc = exp2f(mrun - mnew);
                mrun = mnew;
                lrun *= resc;
                o[0] *= resc; o[1] *= resc; o[2] *= resc; o[3] *= resc;
            }

            float ps = 0.f;
            #pragma unroll
            for (int st = 0; st < 4; ++st)
                #pragma unroll
                for (int r = 0; r < 4; ++r) {
                    float p = exp2f(sv[st][r] - mrun);
                    sv[st][r] = p;
                    ps += p;
                }
            ps += __shfl_xor(ps, 16);
            ps += __shfl_xor(ps, 32);
            lrun += ps;

            // ---- write P single-bf16, wave-private rows ----
            #pragma unroll
            for (int st = 0; st < 4; ++st) {
                bf16x4v pb = { (__bf16)sv[st][0], (__bf16)sv[st][1],
                               (__bf16)sv[st][2], (__bf16)sv[st][3] };
                int off = (prow * 128 + (st * 16 + g * 4) * 2) ^ ((prow & 7) << 4);
                *(bf16x4v*)(lds + PS_ + off) = pb;
            }

            // ---- O^T += V^T . P^T ----
            bf16x8 pf[2];
            #pragma unroll
            for (int kc = 0; kc < 2; ++kc) {
                int off = (prow * 128 + kc * 64 + g * 16) ^ ((prow & 7) << 4);
                pf[kc] = *(const bf16x8*)(lds + PS_ + off);
            }
            #pragma unroll
            for (int dt = 0; dt < 4; ++dt) {
                int vrow = dt * 16 + r15;
                #pragma unroll
                for (int kc = 0; kc < 2; ++kc) {
                    int off = (vrow * 128 + kc * 64 + g * 16) ^ ((vrow & 7) << 4);
                    bf16x8 vh = *(const bf16x8*)(VH + off);
                    bf16x8 vl = *(const bf16x8*)(VL + off);
                    o[dt] = __builtin_amdgcn_mfma_f32_16x16x32_bf16(vh, pf[kc], o[dt], 0, 0, 0);
                    o[dt] = __builtin_amdgcn_mfma_f32_16x16x32_bf16(vl, pf[kc], o[dt], 0, 0, 0);
                }
            }
        }

        __syncthreads();   // vmcnt(0): tile kt+1 resident; all waves done with buf[kt&1]
    }

    // ---- epilogue: O^T[d][q] -> yatt[b][q][h*64+d] ----
    const float inv = 1.f / lrun;
    float* yo = qyatt + ((size_t)b * T_ + qglob) * C_ + h * DK_;
    #pragma unroll
    for (int dt = 0; dt < 4; ++dt)
        #pragma unroll
        for (int r = 0; r < 4; ++r)
            yo[dt * 16 + g * 4 + r] = o[dt][r] * inv;
}

// ============================================================
extern "C" void kernel_launch(void* const* d_in, const int* in_sizes, int n_in,
                              void* d_out, int out_size, void* d_ws, size_t ws_size,
                              hipStream_t stream) {
    const float* x     = (const float*)d_in[0];
    const float* Wqkv  = (const float*)d_in[1];
    const float* bqkv  = (const float*)d_in[2];
    const float* Wproj = (const float*)d_in[3];
    const float* bproj = (const float*)d_in[4];

    float* y     = (float*)d_out;                 // [B,T,C]: q fp32 -> yatt -> final y
    float* k_out = y + (size_t)4194304;           // [B,H,T,DK] (final output)
    float* v_out = y + (size_t)8388608;           // [B,H,T,DK] (final output)

    char* ws = (char*)d_ws;                       // 32 MB, lifetime-aliased:
    char* xp  = ws;                               // [0,16M)  x packed        (phase 1-2)
    char* wqp = ws + ((size_t)16 << 20);          // [16M,28M) Wqkv packed    (phase 1-2)
    char* Kp  = ws;                               // [0,16M)  K packed        (phase 3-4)
    char* Vp  = ws + ((size_t)16 << 20);          // [16M,32M) V^T packed     (phase 3-4)
    char* yap = ws;                               // [0,8M)   yatt packed     (phase 5-6)
    char* wpp = ws + ((size_t)8 << 20);           // [8M,12M) Wproj packed    (phase 5-6)

    pack_a_hl     <<<dim3(32, 32), 256, 0, stream>>>(x, xp);
    pack_bt_hl<32><<<dim3(24, 32), 256, 0, stream>>>(Wqkv, wqp, 3072, 32);
    qkv_gemm_bf16 <<<dim3(32, 24), 256, 0, stream>>>(xp, wqp, bqkv, y, k_out, v_out);
    kv_pack       <<<dim3(32, 32), 256, 0, stream>>>(k_out, v_out, Kp, Vp);
    attn_mfma_kernel<<<dim3(32, 16), 512, 0, stream>>>(y, Kp, Vp);
    pack_a_s      <<<dim3(32, 16), 256, 0, stream>>>(y, yap);
    pack_bt_hl<64><<<dim3(8, 16), 256, 0, stream>>>(Wproj, wpp, 1024, 16);
    proj_gemm_bf16<<<dim3(32, 8), 256, 0, stream>>>(yap, wpp, bproj, y);
}